// Round 11
// baseline (349.170 us; speedup 1.0000x reference)
//
#include <hip/hip_runtime.h>
#include <stdint.h>

typedef unsigned long long u64;
typedef __attribute__((ext_vector_type(8))) short bf16x8;
typedef __attribute__((ext_vector_type(4))) float f32x4;
typedef __attribute__((ext_vector_type(4))) unsigned u32x4;

#define BATCH 512
#define FEAT 256
#define ENC 2048
#define HID 4096
#define CLS 1000
#define KTOT 12288      // 3 * 4096
#define NSPLIT 16
#define KSPLIT 768
#define PARTLD 1024

// ws offsets
#define OFF_ENC2   0
#define OFF_ACT2   131072
#define OFF_TABLE  917504
#define OFF_COUNTS 1703936
#define OFF_WT     1753088
#define OFF_PART   26918912
#define PART_BYTES (16ull * 512 * 1024 * 4)
#define WS_NEED    (OFF_PART + PART_BYTES)

// ---------- fp32 -> bf16 RNE ----------
static __device__ inline unsigned short f2bf(float f) {
    unsigned u = __float_as_uint(f);
    return (unsigned short)((u + 0x7FFFu + ((u >> 16) & 1u)) >> 16);
}

// ---------- async global->LDS, 16B/lane ----------
static __device__ inline void gld16(const void* g, void* s) {
    __builtin_amdgcn_global_load_lds((const __attribute__((address_space(1))) void*)g,
                                     (__attribute__((address_space(3))) void*)s, 16, 0, 0);
}

// ================= kernel 1: fused prep = encode | scan | twt =================
// blocks [0,512): encode   [512,5632): scan   [5632,8704): twt
__global__ void __launch_bounds__(256)
k_prep(const float* __restrict__ x, u64* __restrict__ enc2,
       const float* __restrict__ W0, const float* __restrict__ W1,
       const float* __restrict__ W2,
       uint16_t* __restrict__ table, int* __restrict__ counts,
       const float* __restrict__ out_w, short* __restrict__ wt) {
    __shared__ short tile[64 * 68];
    __shared__ int cnt4[4];
    int bid = blockIdx.x;
    int t = threadIdx.x;
    int lane = t & 63;
    int wv = t >> 6;

    if (bid < 512) {
        int wid = bid * 4 + wv;
        int f = wid >> 3, bg = wid & 7;
        float v = x[(size_t)(bg * 64 + lane) * FEAT + f];
        v = fminf(fmaxf(v, 0.0f), 1.0f);
        int lev = (int)rintf(v * 255.0f);                // RNE == jnp.round
        unsigned gray = (unsigned)(lev ^ (lev >> 1));
        u64 w = 0;
        #pragma unroll
        for (int bit = 0; bit < 8; ++bit) {
            u64 m = __ballot((gray >> bit) & 1u);
            if (lane == bit) w = m;
        }
        if (lane < 8) enc2[(size_t)bg * ENC + f * 8 + lane] = w;
        return;
    }
    if (bid < 5632) {
        // ---- scan: nontemporal streaming reads; LDS-atomic slot compaction ----
        if (t < 4) cnt4[t] = 0;
        __syncthreads();
        int wsid = (bid - 512) * 4 + wv;
        int row, base, cidx;
        if (wsid < HID) { row = wsid; base = 0; cidx = wv; }
        else {
            int w2 = wsid - HID;
            row = HID + (w2 >> 1);
            base = (w2 & 1) * 2048;
            cidx = wv >> 1;
        }
        const float* Wr;
        if (row < HID)          Wr = W0 + (size_t)row * ENC;
        else if (row < 2 * HID) Wr = W1 + (size_t)(row - HID) * HID + base;
        else                    Wr = W2 + (size_t)(row - 2 * HID) * HID + base;
        const u32x4* p4 = (const u32x4*)Wr;
        u32x4 v[8];
        #pragma unroll
        for (int j = 0; j < 8; ++j) v[j] = __builtin_nontemporal_load(p4 + j * 64 + lane);
        uint16_t* te = table + (size_t)row * 32;
        #pragma unroll
        for (int j = 0; j < 8; ++j) {
            unsigned a0 = v[j].x, a1 = v[j].y, a2 = v[j].z, a3 = v[j].w;
            if (a0 | a1 | a2 | a3) {
                int col0 = base + j * 256 + lane * 4;
                if (a0) { int s = atomicAdd(&cnt4[cidx], 1);
                          te[s] = (uint16_t)((unsigned)col0       | ((a0 >> 16) & 0x8000u)); }
                if (a1) { int s = atomicAdd(&cnt4[cidx], 1);
                          te[s] = (uint16_t)((unsigned)(col0 + 1) | ((a1 >> 16) & 0x8000u)); }
                if (a2) { int s = atomicAdd(&cnt4[cidx], 1);
                          te[s] = (uint16_t)((unsigned)(col0 + 2) | ((a2 >> 16) & 0x8000u)); }
                if (a3) { int s = atomicAdd(&cnt4[cidx], 1);
                          te[s] = (uint16_t)((unsigned)(col0 + 3) | ((a3 >> 16) & 0x8000u)); }
            }
        }
        __syncthreads();
        if (lane == 0) counts[row] = cnt4[cidx];
        return;
    }
    {
        // ---- twt: transpose+convert out_w -> wt bf16 (swizzled) ----
        int b2 = bid - 5632;
        int kt = b2 % 192, ct = b2 / 192;
        int k0 = kt * 64, c0 = ct * 64;
        {
            int rrow = t >> 4, c4 = t & 15;
            int c = c0 + c4 * 4;
            #pragma unroll
            for (int rd = 0; rd < 4; ++rd) {
                int kl = rd * 16 + rrow;
                f32x4 vv;
                if (c < CLS)
                    vv = __builtin_nontemporal_load(
                        (const f32x4*)&out_w[(size_t)(k0 + kl) * CLS + c]);
                else { vv.x = 0.0f; vv.y = 0.0f; vv.z = 0.0f; vv.w = 0.0f; }
                short* d = &tile[kl * 68 + c4 * 4];
                d[0] = (short)f2bf(vv.x); d[1] = (short)f2bf(vv.y);
                d[2] = (short)f2bf(vv.z); d[3] = (short)f2bf(vv.w);
            }
        }
        __syncthreads();
        {
            int chunk = t & 7, cl2 = t >> 3;
            #pragma unroll
            for (int rd = 0; rd < 2; ++rd) {
                int c_local = rd * 32 + cl2;
                int c = c0 + c_local;
                unsigned s8[8];
                #pragma unroll
                for (int j = 0; j < 8; ++j)
                    s8[j] = (unsigned)(unsigned short)tile[(chunk * 8 + j) * 68 + c_local];
                uint4 pk;
                pk.x = s8[0] | (s8[1] << 16);
                pk.y = s8[2] | (s8[3] << 16);
                pk.z = s8[4] | (s8[5] << 16);
                pk.w = s8[6] | (s8[7] << 16);
                *(uint4*)&wt[(size_t)c * KTOT + k0 + ((chunk ^ (c & 7)) * 8)] = pk;
            }
        }
    }
}

// ================= kernel 2: layer via LDS gather =====================================
// Block pins (bg, 64-neuron group). Stages prev slice (16/32 KB) into LDS by async DMA;
// gathers are ds_read_b64 with wave-uniform address (broadcast, conflict-free).
__global__ void __launch_bounds__(256)
k_layer(const u64* __restrict__ prev2, int Kwords,
        const uint16_t* __restrict__ table_l, const int* __restrict__ counts_l,
        u64* __restrict__ actout) {
    __shared__ __attribute__((aligned(16))) u64 sprev[4096];    // up to 32 KB
    int bid = blockIdx.x, t = threadIdx.x;
    int lane = t & 63, wv = t >> 6;
    int bg = bid & 7, nb = bid >> 3;          // 64 neurons per block
    const char* src = (const char*)(prev2 + (size_t)bg * Kwords);
    int nbytes = Kwords * 8;
    for (int it = t * 16; it < nbytes; it += 4096)
        gld16(src + it, ((char*)sprev) + it);
    __syncthreads();
    int n0 = nb * 64 + wv * 16;
    #pragma unroll 4
    for (int v = 0; v < 16; ++v) {
        int n = n0 + v;
        const uint4* tq = (const uint4*)(table_l + (size_t)n * 32);
        int cnt = counts_l[n];
        int z = 0;
        #pragma unroll
        for (int q = 0; q < 4; ++q) {
            uint4 e4 = tq[q];
            unsigned es[4] = {e4.x, e4.y, e4.z, e4.w};
            #pragma unroll
            for (int h = 0; h < 4; ++h) {
                #pragma unroll
                for (int s2 = 0; s2 < 2; ++s2) {
                    int e = q * 8 + h * 2 + s2;
                    if (e < cnt) {
                        unsigned ent = (es[h] >> (s2 * 16)) & 0xFFFFu;
                        u64 w = sprev[ent & 0x7FFFu];    // LDS broadcast
                        int bit = (int)((w >> lane) & 1ull);
                        z += (ent & 0x8000u) ? -bit : bit;
                    }
                }
            }
        }
        u64 res = __ballot(z >= 4);
        if (lane == 0) actout[(size_t)bg * HID + n] = res;
    }
}

// ================= kernel 3: GEMM (R9 mapping), in-kernel A bit-expansion =============
template<int MODE>   // 0: partial stores, 1: atomics into out
__global__ void __launch_bounds__(256)
k_gemm(const u64* __restrict__ act2, const short* __restrict__ wt,
       float* __restrict__ out, float* __restrict__ part) {
    __shared__ __attribute__((aligned(16))) short As[128 * 64];
    __shared__ __attribute__((aligned(16))) short Bs[128 * 64];
    int bid = blockIdx.x;
    int mt = bid & 3, nt = (bid >> 2) & 7, ks = bid >> 5;   // R2/R9-proven mapping
    int tid = threadIdx.x, lane = tid & 63;
    int wv = tid >> 6, waveM = wv & 1, waveN = wv >> 1;
    int quad = lane >> 4, cl = lane & 15;
    f32x4 acc[4][4] = {};
    const char* Bb = (const char*)(wt + (size_t)nt * 128 * KTOT + ks * KSPLIT);
    int r = tid >> 3, sub = tid & 7;
    for (int kk = 0; kk < KSPLIT; kk += 64) {
        #pragma unroll
        for (int rd = 0; rd < 4; ++rd) {
            size_t go = (size_t)(r + rd * 32) * (KTOT * 2) + kk * 2 + sub * 16;
            gld16(Bb + go, &Bs[(tid + rd * 256) * 8]);
        }
        {
            int kabs = ks * KSPLIT + kk;
            int l = kabs >> 12, nk = kabs & 4095;
            #pragma unroll
            for (int i = 0; i < 4; ++i) {
                int item = i * 256 + tid;
                int rr = item >> 3, gg = item & 7;
                const u64* w8 = act2 + ((size_t)(l * 8 + mt * 2 + (rr >> 6))) * HID + nk + gg * 8;
                int bl = rr & 63;
                unsigned sh[8];
                #pragma unroll
                for (int j = 0; j < 8; ++j)
                    sh[j] = (unsigned)((w8[j] >> bl) & 1ull) * 0x3F80u;
                uint4 pk;
                pk.x = sh[0] | (sh[1] << 16);
                pk.y = sh[2] | (sh[3] << 16);
                pk.z = sh[4] | (sh[5] << 16);
                pk.w = sh[6] | (sh[7] << 16);
                *(uint4*)&As[rr * 64 + ((gg ^ (rr & 7)) * 8)] = pk;
            }
        }
        __syncthreads();
        #pragma unroll
        for (int s = 0; s < 2; ++s) {
            int xr = ((s * 4 + quad) ^ (cl & 7)) * 8;
            bf16x8 af[4], bfr[4];
            #pragma unroll
            for (int mf = 0; mf < 4; ++mf)
                af[mf] = *(const bf16x8*)&As[(waveM * 64 + mf * 16 + cl) * 64 + xr];
            #pragma unroll
            for (int nf = 0; nf < 4; ++nf)
                bfr[nf] = *(const bf16x8*)&Bs[(waveN * 64 + nf * 16 + cl) * 64 + xr];
            #pragma unroll
            for (int mf = 0; mf < 4; ++mf)
                #pragma unroll
                for (int nf = 0; nf < 4; ++nf)
                    acc[mf][nf] = __builtin_amdgcn_mfma_f32_16x16x32_bf16(
                        af[mf], bfr[nf], acc[mf][nf], 0, 0, 0);
        }
        __syncthreads();
    }
    if (MODE == 0) {
        float* pbase = part + (size_t)ks * (BATCH * PARTLD);
        #pragma unroll
        for (int mf = 0; mf < 4; ++mf)
            #pragma unroll
            for (int nf = 0; nf < 4; ++nf) {
                int cp = nt * 128 + waveN * 64 + nf * 16 + cl;
                #pragma unroll
                for (int rr = 0; rr < 4; ++rr) {
                    int mg = mt * 128 + waveM * 64 + mf * 16 + quad * 4 + rr;
                    pbase[(size_t)mg * PARTLD + cp] = acc[mf][nf][rr];
                }
            }
    } else {
        #pragma unroll
        for (int mf = 0; mf < 4; ++mf)
            #pragma unroll
            for (int nf = 0; nf < 4; ++nf) {
                int cp = nt * 128 + waveN * 64 + nf * 16 + cl;
                if (cp < CLS) {
                    #pragma unroll
                    for (int rr = 0; rr < 4; ++rr) {
                        int mg = mt * 128 + waveM * 64 + mf * 16 + quad * 4 + rr;
                        atomicAdd(&out[(size_t)mg * CLS + cp], acc[mf][nf][rr]);
                    }
                }
            }
    }
}

// ================= kernel 4: reduce split-K partials into out (float4) ===============
__global__ void k_reduce(const float* __restrict__ part, float* __restrict__ out) {
    int idx = blockIdx.x * blockDim.x + threadIdx.x;     // 512*250 float4s
    if (idx >= BATCH * (CLS / 4)) return;
    int b = idx / (CLS / 4), c4 = idx - b * (CLS / 4);
    f32x4 s = {0.f, 0.f, 0.f, 0.f};
    #pragma unroll
    for (int sp = 0; sp < NSPLIT; ++sp) {
        f32x4 v = *(const f32x4*)&part[((size_t)sp * BATCH + b) * PARTLD + c4 * 4];
        s.x += v.x; s.y += v.y; s.z += v.z; s.w += v.w;
    }
    *(f32x4*)&out[(size_t)b * CLS + c4 * 4] = s;
}

extern "C" void kernel_launch(void* const* d_in, const int* in_sizes, int n_in,
                              void* d_out, int out_size, void* d_ws, size_t ws_size,
                              hipStream_t stream) {
    const float* x     = (const float*)d_in[0];
    const float* W0    = (const float*)d_in[1];
    const float* W1    = (const float*)d_in[2];
    const float* W2    = (const float*)d_in[3];
    const float* out_w = (const float*)d_in[4];
    float* out = (float*)d_out;
    char* ws = (char*)d_ws;

    u64*      enc2   = (u64*)(ws + OFF_ENC2);
    u64*      act2   = (u64*)(ws + OFF_ACT2);
    uint16_t* table  = (uint16_t*)(ws + OFF_TABLE);
    int*      counts = (int*)(ws + OFF_COUNTS);
    short*    wt     = (short*)(ws + OFF_WT);
    float*    part   = (float*)(ws + OFF_PART);

    int use_part = (ws_size >= (size_t)WS_NEED) ? 1 : 0;

    hipLaunchKernelGGL(k_prep, dim3(8704), dim3(256), 0, stream,
                       x, enc2, W0, W1, W2, table, counts, out_w, wt);
    if (!use_part)
        (void)hipMemsetAsync(d_out, 0, (size_t)BATCH * CLS * sizeof(float), stream);

    hipLaunchKernelGGL(k_layer, dim3(512), dim3(256), 0, stream,
                       enc2, ENC, table, counts, act2);
    hipLaunchKernelGGL(k_layer, dim3(512), dim3(256), 0, stream,
                       act2, HID, table + (size_t)HID * 32, counts + HID, act2 + 8 * HID);
    hipLaunchKernelGGL(k_layer, dim3(512), dim3(256), 0, stream,
                       act2 + 8 * HID, HID, table + (size_t)2 * HID * 32, counts + 2 * HID,
                       act2 + 16 * HID);
    if (use_part) {
        hipLaunchKernelGGL((k_gemm<0>), dim3(512), dim3(256), 0, stream,
                           act2, wt, out, part);
        hipLaunchKernelGGL(k_reduce, dim3((BATCH * (CLS / 4) + 255) / 256), dim3(256), 0,
                           stream, part, out);
    } else {
        hipLaunchKernelGGL((k_gemm<1>), dim3(512), dim3(256), 0, stream,
                           act2, wt, out, part);
    }
}

// Round 12
// 279.043 us; speedup vs baseline: 1.2513x; 1.2513x over previous
//
#include <hip/hip_runtime.h>
#include <stdint.h>

typedef unsigned long long u64;
typedef __attribute__((ext_vector_type(8))) short bf16x8;
typedef __attribute__((ext_vector_type(4))) float f32x4;
typedef __attribute__((ext_vector_type(4))) unsigned u32x4;

#define BATCH 512
#define FEAT 256
#define ENC 2048
#define HID 4096
#define CLS 1000
#define KTOT 12288      // 3 * 4096
#define NSPLIT 16
#define KSPLIT 768
#define PARTLD 1024

// ws offsets
#define OFF_ENC2   0
#define OFF_ACT2   131072
#define OFF_TABLE  917504
#define OFF_SGN    1703936
#define OFF_WT     2097152
#define OFF_PART   27262976
#define PART_BYTES (16ull * 512 * 1024 * 4)
#define WS_NEED    (OFF_PART + PART_BYTES)

// ---------- fp32 -> bf16 RNE ----------
static __device__ inline unsigned short f2bf(float f) {
    unsigned u = __float_as_uint(f);
    return (unsigned short)((u + 0x7FFFu + ((u >> 16) & 1u)) >> 16);
}

// ---------- async global->LDS, 16B/lane ----------
static __device__ inline void gld16(const void* g, void* s) {
    __builtin_amdgcn_global_load_lds((const __attribute__((address_space(1))) void*)g,
                                     (__attribute__((address_space(3))) void*)s, 16, 0, 0);
}

// ================= kernel 1: fused prep = encode | scan | twt =================
// blocks [0,512): encode   [512,5632): scan   [5632,8704): twt
__global__ void __launch_bounds__(256)
k_prep(const float* __restrict__ x, u64* __restrict__ enc2,
       const float* __restrict__ W0, const float* __restrict__ W1,
       const float* __restrict__ W2,
       uint16_t* __restrict__ table, char* __restrict__ sgn,
       const float* __restrict__ out_w, short* __restrict__ wt) {
    __shared__ short tile[64 * 68];
    __shared__ int cnt4[4];
    int bid = blockIdx.x;
    int t = threadIdx.x;
    int lane = t & 63;
    int wv = t >> 6;

    if (bid < 512) {
        int wid = bid * 4 + wv;
        int f = wid >> 3, bg = wid & 7;
        float v = x[(size_t)(bg * 64 + lane) * FEAT + f];
        v = fminf(fmaxf(v, 0.0f), 1.0f);
        int lev = (int)rintf(v * 255.0f);                // RNE == jnp.round
        unsigned gray = (unsigned)(lev ^ (lev >> 1));
        u64 w = 0;
        #pragma unroll
        for (int bit = 0; bit < 8; ++bit) {
            u64 m = __ballot((gray >> bit) & 1u);
            if (lane == bit) w = m;
        }
        if (lane < 8) enc2[(size_t)bg * ENC + f * 8 + lane] = w;
        return;
    }
    if (bid < 5632) {
        // ---- scan: nontemporal streaming; branch-free padded table + int8 signs ----
        int wsid = (bid - 512) * 4 + wv;
        int row, base, cidx;
        if (wsid < HID) { row = wsid; base = 0; cidx = wv; }
        else {
            int w2 = wsid - HID;
            row = HID + (w2 >> 1);
            base = (w2 & 1) * 2048;
            cidx = wv >> 1;
        }
        uint16_t* te = table + (size_t)row * 32;
        char*     se = sgn + (size_t)row * 32;
        // zero-pad row (redundant across waves sharing a row: benign, same value)
        if (lane < 8) ((u64*)te)[lane] = 0;
        if (lane < 4) ((u64*)se)[lane] = 0;
        if (t < 4) cnt4[t] = 0;
        __syncthreads();
        const float* Wr;
        if (row < HID)          Wr = W0 + (size_t)row * ENC;
        else if (row < 2 * HID) Wr = W1 + (size_t)(row - HID) * HID + base;
        else                    Wr = W2 + (size_t)(row - 2 * HID) * HID + base;
        const u32x4* p4 = (const u32x4*)Wr;
        u32x4 v[8];
        #pragma unroll
        for (int j = 0; j < 8; ++j) v[j] = __builtin_nontemporal_load(p4 + j * 64 + lane);
        #pragma unroll
        for (int j = 0; j < 8; ++j) {
            unsigned a0 = v[j].x, a1 = v[j].y, a2 = v[j].z, a3 = v[j].w;
            if (a0 | a1 | a2 | a3) {
                int col0 = base + j * 256 + lane * 4;
                if (a0) { int s = atomicAdd(&cnt4[cidx], 1);
                          te[s] = (uint16_t)col0;       se[s] = (a0 >> 31) ? -1 : 1; }
                if (a1) { int s = atomicAdd(&cnt4[cidx], 1);
                          te[s] = (uint16_t)(col0 + 1); se[s] = (a1 >> 31) ? -1 : 1; }
                if (a2) { int s = atomicAdd(&cnt4[cidx], 1);
                          te[s] = (uint16_t)(col0 + 2); se[s] = (a2 >> 31) ? -1 : 1; }
                if (a3) { int s = atomicAdd(&cnt4[cidx], 1);
                          te[s] = (uint16_t)(col0 + 3); se[s] = (a3 >> 31) ? -1 : 1; }
            }
        }
        return;
    }
    {
        // ---- twt: transpose+convert out_w -> wt bf16 (swizzled) ----
        int b2 = bid - 5632;
        int kt = b2 % 192, ct = b2 / 192;
        int k0 = kt * 64, c0 = ct * 64;
        {
            int rrow = t >> 4, c4 = t & 15;
            int c = c0 + c4 * 4;
            #pragma unroll
            for (int rd = 0; rd < 4; ++rd) {
                int kl = rd * 16 + rrow;
                f32x4 vv;
                if (c < CLS)
                    vv = __builtin_nontemporal_load(
                        (const f32x4*)&out_w[(size_t)(k0 + kl) * CLS + c]);
                else { vv.x = 0.0f; vv.y = 0.0f; vv.z = 0.0f; vv.w = 0.0f; }
                short* d = &tile[kl * 68 + c4 * 4];
                d[0] = (short)f2bf(vv.x); d[1] = (short)f2bf(vv.y);
                d[2] = (short)f2bf(vv.z); d[3] = (short)f2bf(vv.w);
            }
        }
        __syncthreads();
        {
            int chunk = t & 7, cl2 = t >> 3;
            #pragma unroll
            for (int rd = 0; rd < 2; ++rd) {
                int c_local = rd * 32 + cl2;
                int c = c0 + c_local;
                unsigned s8[8];
                #pragma unroll
                for (int j = 0; j < 8; ++j)
                    s8[j] = (unsigned)(unsigned short)tile[(chunk * 8 + j) * 68 + c_local];
                uint4 pk;
                pk.x = s8[0] | (s8[1] << 16);
                pk.y = s8[2] | (s8[3] << 16);
                pk.z = s8[4] | (s8[5] << 16);
                pk.w = s8[6] | (s8[7] << 16);
                *(uint4*)&wt[(size_t)c * KTOT + k0 + ((chunk ^ (c & 7)) * 8)] = pk;
            }
        }
    }
}

// ================= kernel 2: layer, branch-free, signs-mad, full occupancy ===========
// wave = (n, bg); 32 unconditional broadcast loads per neuron, sign in {+1,-1,0}
__global__ void __launch_bounds__(256)
k_layer(const u64* __restrict__ prev2, int Kwords,
        const uint16_t* __restrict__ table_l, const char* __restrict__ sgn_l,
        u64* __restrict__ actout) {
    int wid = __builtin_amdgcn_readfirstlane(blockIdx.x * 4 + (threadIdx.x >> 6));
    int lane = threadIdx.x & 63;
    int n = wid >> 3, bg = wid & 7;
    const u64* prow = prev2 + (size_t)bg * Kwords;
    const uint4* tq = (const uint4*)(table_l + (size_t)n * 32);
    const int*  sq = (const int*)(sgn_l + (size_t)n * 32);
    int z = 0;
    #pragma unroll
    for (int q = 0; q < 4; ++q) {
        uint4 e4 = tq[q];
        int s0 = sq[q * 2], s1 = sq[q * 2 + 1];      // 8 int8 signs
        unsigned es[4] = {e4.x, e4.y, e4.z, e4.w};
        u64 w[8];
        #pragma unroll
        for (int h = 0; h < 4; ++h) {
            w[h * 2]     = prow[es[h] & 0xFFFFu];
            w[h * 2 + 1] = prow[es[h] >> 16];
        }
        #pragma unroll
        for (int j = 0; j < 8; ++j) {
            int bit = (int)((w[j] >> lane) & 1ull);
            int sw = (j < 4) ? s0 : s1;
            int s = (sw << (24 - (j & 3) * 8)) >> 24;     // sext byte
            z += s * bit;
        }
    }
    u64 res = __ballot(z >= 4);
    if (lane == 0) actout[(size_t)bg * HID + n] = res;
}

// ================= kernel 3: GEMM (R9 mapping), in-kernel A bit-expansion =============
template<int MODE>   // 0: partial stores, 1: atomics into out
__global__ void __launch_bounds__(256)
k_gemm(const u64* __restrict__ act2, const short* __restrict__ wt,
       float* __restrict__ out, float* __restrict__ part) {
    __shared__ __attribute__((aligned(16))) short As[128 * 64];
    __shared__ __attribute__((aligned(16))) short Bs[128 * 64];
    int bid = blockIdx.x;
    int mt = bid & 3, nt = (bid >> 2) & 7, ks = bid >> 5;
    int tid = threadIdx.x, lane = tid & 63;
    int wv = tid >> 6, waveM = wv & 1, waveN = wv >> 1;
    int quad = lane >> 4, cl = lane & 15;
    f32x4 acc[4][4] = {};
    const char* Bb = (const char*)(wt + (size_t)nt * 128 * KTOT + ks * KSPLIT);
    int r = tid >> 3, sub = tid & 7;
    for (int kk = 0; kk < KSPLIT; kk += 64) {
        #pragma unroll
        for (int rd = 0; rd < 4; ++rd) {
            size_t go = (size_t)(r + rd * 32) * (KTOT * 2) + kk * 2 + sub * 16;
            gld16(Bb + go, &Bs[(tid + rd * 256) * 8]);
        }
        {
            int kabs = ks * KSPLIT + kk;
            int l = kabs >> 12, nk = kabs & 4095;
            #pragma unroll
            for (int i = 0; i < 4; ++i) {
                int item = i * 256 + tid;
                int rr = item >> 3, gg = item & 7;
                const u64* w8 = act2 + ((size_t)(l * 8 + mt * 2 + (rr >> 6))) * HID + nk + gg * 8;
                int bl = rr & 63;
                unsigned sh[8];
                #pragma unroll
                for (int j = 0; j < 8; ++j)
                    sh[j] = (unsigned)((w8[j] >> bl) & 1ull) * 0x3F80u;
                uint4 pk;
                pk.x = sh[0] | (sh[1] << 16);
                pk.y = sh[2] | (sh[3] << 16);
                pk.z = sh[4] | (sh[5] << 16);
                pk.w = sh[6] | (sh[7] << 16);
                *(uint4*)&As[rr * 64 + ((gg ^ (rr & 7)) * 8)] = pk;
            }
        }
        __syncthreads();
        #pragma unroll
        for (int s = 0; s < 2; ++s) {
            int xr = ((s * 4 + quad) ^ (cl & 7)) * 8;
            bf16x8 af[4], bfr[4];
            #pragma unroll
            for (int mf = 0; mf < 4; ++mf)
                af[mf] = *(const bf16x8*)&As[(waveM * 64 + mf * 16 + cl) * 64 + xr];
            #pragma unroll
            for (int nf = 0; nf < 4; ++nf)
                bfr[nf] = *(const bf16x8*)&Bs[(waveN * 64 + nf * 16 + cl) * 64 + xr];
            #pragma unroll
            for (int mf = 0; mf < 4; ++mf)
                #pragma unroll
                for (int nf = 0; nf < 4; ++nf)
                    acc[mf][nf] = __builtin_amdgcn_mfma_f32_16x16x32_bf16(
                        af[mf], bfr[nf], acc[mf][nf], 0, 0, 0);
        }
        __syncthreads();
    }
    if (MODE == 0) {
        float* pbase = part + (size_t)ks * (BATCH * PARTLD);
        #pragma unroll
        for (int mf = 0; mf < 4; ++mf)
            #pragma unroll
            for (int nf = 0; nf < 4; ++nf) {
                int cp = nt * 128 + waveN * 64 + nf * 16 + cl;
                #pragma unroll
                for (int rr = 0; rr < 4; ++rr) {
                    int mg = mt * 128 + waveM * 64 + mf * 16 + quad * 4 + rr;
                    pbase[(size_t)mg * PARTLD + cp] = acc[mf][nf][rr];
                }
            }
    } else {
        #pragma unroll
        for (int mf = 0; mf < 4; ++mf)
            #pragma unroll
            for (int nf = 0; nf < 4; ++nf) {
                int cp = nt * 128 + waveN * 64 + nf * 16 + cl;
                if (cp < CLS) {
                    #pragma unroll
                    for (int rr = 0; rr < 4; ++rr) {
                        int mg = mt * 128 + waveM * 64 + mf * 16 + quad * 4 + rr;
                        atomicAdd(&out[(size_t)mg * CLS + cp], acc[mf][nf][rr]);
                    }
                }
            }
    }
}

// ================= kernel 4: reduce split-K partials into out (float4) ===============
__global__ void k_reduce(const float* __restrict__ part, float* __restrict__ out) {
    int idx = blockIdx.x * blockDim.x + threadIdx.x;     // 512*250 float4s
    if (idx >= BATCH * (CLS / 4)) return;
    int b = idx / (CLS / 4), c4 = idx - b * (CLS / 4);
    f32x4 s = {0.f, 0.f, 0.f, 0.f};
    #pragma unroll
    for (int sp = 0; sp < NSPLIT; ++sp) {
        f32x4 v = *(const f32x4*)&part[((size_t)sp * BATCH + b) * PARTLD + c4 * 4];
        s.x += v.x; s.y += v.y; s.z += v.z; s.w += v.w;
    }
    *(f32x4*)&out[(size_t)b * CLS + c4 * 4] = s;
}

extern "C" void kernel_launch(void* const* d_in, const int* in_sizes, int n_in,
                              void* d_out, int out_size, void* d_ws, size_t ws_size,
                              hipStream_t stream) {
    const float* x     = (const float*)d_in[0];
    const float* W0    = (const float*)d_in[1];
    const float* W1    = (const float*)d_in[2];
    const float* W2    = (const float*)d_in[3];
    const float* out_w = (const float*)d_in[4];
    float* out = (float*)d_out;
    char* ws = (char*)d_ws;

    u64*      enc2   = (u64*)(ws + OFF_ENC2);
    u64*      act2   = (u64*)(ws + OFF_ACT2);
    uint16_t* table  = (uint16_t*)(ws + OFF_TABLE);
    char*     sgn    = (char*)(ws + OFF_SGN);
    short*    wt     = (short*)(ws + OFF_WT);
    float*    part   = (float*)(ws + OFF_PART);

    int use_part = (ws_size >= (size_t)WS_NEED) ? 1 : 0;

    hipLaunchKernelGGL(k_prep, dim3(8704), dim3(256), 0, stream,
                       x, enc2, W0, W1, W2, table, sgn, out_w, wt);
    if (!use_part)
        (void)hipMemsetAsync(d_out, 0, (size_t)BATCH * CLS * sizeof(float), stream);

    hipLaunchKernelGGL(k_layer, dim3(8192), dim3(256), 0, stream,
                       enc2, ENC, table, sgn, act2);
    hipLaunchKernelGGL(k_layer, dim3(8192), dim3(256), 0, stream,
                       act2, HID, table + (size_t)HID * 32, sgn + (size_t)HID * 32,
                       act2 + 8 * HID);
    hipLaunchKernelGGL(k_layer, dim3(8192), dim3(256), 0, stream,
                       act2 + 8 * HID, HID, table + (size_t)2 * HID * 32,
                       sgn + (size_t)2 * HID * 32, act2 + 16 * HID);
    if (use_part) {
        hipLaunchKernelGGL((k_gemm<0>), dim3(512), dim3(256), 0, stream,
                           act2, wt, out, part);
        hipLaunchKernelGGL(k_reduce, dim3((BATCH * (CLS / 4) + 255) / 256), dim3(256), 0,
                           stream, part, out);
    } else {
        hipLaunchKernelGGL((k_gemm<1>), dim3(512), dim3(256), 0, stream,
                           act2, wt, out, part);
    }
}